// Round 2
// baseline (1561.254 us; speedup 1.0000x reference)
//
#include <hip/hip_runtime.h>
#include <hip/hip_bf16.h>

// Problem constants
#define Bz 16
#define Nn 512
#define Dd 512
#define Hh 8
#define HD 64

// ---------------------------------------------------------------------------
// Kernel 1: build P = row-normalized masked adjacency. One wave per (b, row).
// ---------------------------------------------------------------------------
__global__ __launch_bounds__(64)
void computeP(const float* __restrict__ adj, const int* __restrict__ mask,
              float* __restrict__ P)
{
    const int i = blockIdx.x;
    const int b = blockIdx.y;
    const int lane = threadIdx.x;           // 0..63
    const float* arow = adj + ((long)b * Nn + i) * Nn;
    const int*   mrow = mask + (long)b * Nn;
    const bool mi = (mrow[i] != 0);

    float vals[8];
    float s = 0.f;
    #pragma unroll
    for (int t = 0; t < 2; ++t) {
        const int c = lane * 4 + t * 256;
        float4 a4 = *(const float4*)&arow[c];
        int4   m4 = *(const int4*)&mrow[c];
        float v0 = (mi && m4.x) ? a4.x : 0.f;
        float v1 = (mi && m4.y) ? a4.y : 0.f;
        float v2 = (mi && m4.z) ? a4.z : 0.f;
        float v3 = (mi && m4.w) ? a4.w : 0.f;
        vals[t*4+0] = v0; vals[t*4+1] = v1; vals[t*4+2] = v2; vals[t*4+3] = v3;
        s += v0 + v1 + v2 + v3;
    }
    #pragma unroll
    for (int o = 1; o < 64; o <<= 1) s += __shfl_xor(s, o);
    const float den = (s == 0.f) ? 1.f : s;

    float* prow = P + ((long)b * Nn + i) * Nn;
    #pragma unroll
    for (int t = 0; t < 2; ++t) {
        const int c = lane * 4 + t * 256;
        float4 o4;
        o4.x = vals[t*4+0] / den;
        o4.y = vals[t*4+1] / den;
        o4.z = vals[t*4+2] / den;
        o4.w = vals[t*4+3] / den;
        *(float4*)&prow[c] = o4;
    }
}

// ---------------------------------------------------------------------------
// Kernel 2: batched fp32 GEMM, 128x128 tile, BK=16, 256 threads, 8x8/thread.
//   BT=false: C = A[MxK] @ B[KxN]            (row-major)
//   BT=true : C = A[MxK] @ B[NxK]^T          (B row-major [N][K])
//   BIAS    : C[r][c] += bias[c]
// All dims must divide the tile (M%128==0, N%128==0, K%16==0).
// ---------------------------------------------------------------------------
template<bool BT, bool BIAS>
__global__ __launch_bounds__(256)
void gemm128(const float* __restrict__ A, const float* __restrict__ Bm,
             const float* __restrict__ bias, float* __restrict__ C,
             int M, int N, int K, long sA, long sB, long sC)
{
    __shared__ float As[16][128];   // k-major
    __shared__ float Bs[16][128];

    const int bz = blockIdx.z;
    A  += (long)bz * sA;
    Bm += (long)bz * sB;
    C  += (long)bz * sC;
    const int bm = blockIdx.y * 128;
    const int bn = blockIdx.x * 128;
    const int tid = threadIdx.x;
    const int tx = tid & 15;        // 0..15 -> cols tx*4 and 64+tx*4
    const int ty = tid >> 4;        // 0..15 -> rows ty*4 and 64+ty*4

    float acc[8][8];
    #pragma unroll
    for (int i = 0; i < 8; ++i)
        #pragma unroll
        for (int j = 0; j < 8; ++j) acc[i][j] = 0.f;

    for (int k0 = 0; k0 < K; k0 += 16) {
        // ---- stage A (transposed store: As[k][m]) ----
        #pragma unroll
        for (int i = 0; i < 2; ++i) {
            const int r = (tid >> 2) + i * 64;
            const int c = (tid & 3) * 4;
            float4 a4 = *(const float4*)&A[(long)(bm + r) * K + k0 + c];
            As[c+0][r] = a4.x; As[c+1][r] = a4.y;
            As[c+2][r] = a4.z; As[c+3][r] = a4.w;
        }
        // ---- stage B ----
        if (!BT) {
            #pragma unroll
            for (int i = 0; i < 2; ++i) {
                const int kk = (tid >> 5) + i * 8;
                const int c  = (tid & 31) * 4;
                *(float4*)&Bs[kk][c] =
                    *(const float4*)&Bm[(long)(k0 + kk) * N + bn + c];
            }
        } else {
            #pragma unroll
            for (int i = 0; i < 2; ++i) {
                const int cc = (tid >> 2) + i * 64;
                const int kk = (tid & 3) * 4;
                float4 b4 = *(const float4*)&Bm[(long)(bn + cc) * K + k0 + kk];
                Bs[kk+0][cc] = b4.x; Bs[kk+1][cc] = b4.y;
                Bs[kk+2][cc] = b4.z; Bs[kk+3][cc] = b4.w;
            }
        }
        __syncthreads();

        #pragma unroll
        for (int kk = 0; kk < 16; ++kk) {
            float a[8], bb[8];
            *(float4*)&a[0]  = *(const float4*)&As[kk][ty*4];
            *(float4*)&a[4]  = *(const float4*)&As[kk][64 + ty*4];
            *(float4*)&bb[0] = *(const float4*)&Bs[kk][tx*4];
            *(float4*)&bb[4] = *(const float4*)&Bs[kk][64 + tx*4];
            #pragma unroll
            for (int i = 0; i < 8; ++i)
                #pragma unroll
                for (int j = 0; j < 8; ++j)
                    acc[i][j] = fmaf(a[i], bb[j], acc[i][j]);
        }
        __syncthreads();
    }

    float bv[8];
    if (BIAS) {
        *(float4*)&bv[0] = *(const float4*)&bias[bn + tx*4];
        *(float4*)&bv[4] = *(const float4*)&bias[bn + 64 + tx*4];
    }
    #pragma unroll
    for (int i = 0; i < 8; ++i) {
        const int r = bm + ((i < 4) ? (ty*4 + i) : (64 + ty*4 + (i - 4)));
        float o0[4], o1[4];
        #pragma unroll
        for (int j = 0; j < 4; ++j) {
            o0[j] = acc[i][j]     + (BIAS ? bv[j]     : 0.f);
            o1[j] = acc[i][j + 4] + (BIAS ? bv[j + 4] : 0.f);
        }
        *(float4*)&C[(long)r * N + bn + tx*4]      = *(float4*)o0;
        *(float4*)&C[(long)r * N + bn + 64 + tx*4] = *(float4*)o1;
    }
}

// ---------------------------------------------------------------------------
// Kernel 3: attention. One block per (b, h, 16-row q-tile). 256 threads.
//   - scores [16][512] in LDS (padded stride 516)
//   - edge-FFN bias computed inline from the 5 power matrices
//   - full-row softmax (16-lane shuffle groups)
//   - head-mean of attn atomically accumulated into wout
//   - ctx written to [B][N][D] layout for the final NT GEMM
// ---------------------------------------------------------------------------
#define TQ 16

__global__ __launch_bounds__(256)
void attn_kernel(const float* __restrict__ qkv, const float* __restrict__ powers,
                 const int* __restrict__ mask,
                 const float* __restrict__ w1, const float* __restrict__ b1,
                 const float* __restrict__ w2, const float* __restrict__ b2,
                 float* __restrict__ ctx, float* __restrict__ wout)
{
    const long NN = (long)Nn * Nn;
    const int qt = blockIdx.x, h = blockIdx.y, b = blockIdx.z;
    const int q0 = qt * TQ;
    const int tid = threadIdx.x;

    __shared__ float sc[TQ][516];     // scores / probs (padded: 516%32==4)
    __shared__ float qs[TQ][68];      // q tile (stride 68: 272B, 16B aligned)
    __shared__ float kv[64][68];      // k/v tile
    __shared__ float sw1[6][12], sb1[12], sw2[12][8], sb2[8];

    if (tid < 72)        sw1[tid / 12][tid % 12] = w1[tid];
    else if (tid < 84)   sb1[tid - 72] = b1[tid - 72];
    else if (tid < 180)  sw2[(tid - 84) / 8][(tid - 84) % 8] = w2[tid - 84];
    else if (tid < 188)  sb2[tid - 180] = b2[tid - 180];

    {   // load q tile
        const int r  = tid >> 4;
        const int d4 = (tid & 15) * 4;
        *(float4*)&qs[r][d4] =
            *(const float4*)&qkv[((long)b * Nn + q0 + r) * (3 * Dd) + h * HD + d4];
    }
    __syncthreads();

    const int qi = tid & 15;     // q row within tile
    const int kg = tid >> 4;     // key group (4 keys each)
    const int qrow = q0 + qi;

    // ------------------ pass 1: scores ------------------
    for (int kt = 0; kt < 8; ++kt) {
        #pragma unroll
        for (int i = 0; i < 4; ++i) {
            const int kk = (tid >> 4) + i * 16;
            const int d4 = (tid & 15) * 4;
            *(float4*)&kv[kk][d4] =
                *(const float4*)&qkv[((long)b * Nn + kt * 64 + kk) * (3 * Dd)
                                     + Dd + h * HD + d4];
        }
        __syncthreads();

        float s4[4] = {0.f, 0.f, 0.f, 0.f};
        #pragma unroll
        for (int d4 = 0; d4 < 64; d4 += 4) {
            float4 q4 = *(const float4*)&qs[qi][d4];
            #pragma unroll
            for (int j = 0; j < 4; ++j) {
                float4 k4 = *(const float4*)&kv[kg * 4 + j][d4];
                s4[j] += q4.x * k4.x + q4.y * k4.y + q4.z * k4.z + q4.w * k4.w;
            }
        }

        const int kjb = kt * 64 + kg * 4;
        float xp[5][4];
        #pragma unroll
        for (int s = 0; s < 5; ++s) {
            float4 t = *(const float4*)&powers[((long)(s * Bz + b)) * NN
                                               + (long)qrow * Nn + kjb];
            xp[s][0] = t.x; xp[s][1] = t.y; xp[s][2] = t.z; xp[s][3] = t.w;
        }
        #pragma unroll
        for (int j = 0; j < 4; ++j) {
            const int kj = kjb + j;
            float bias_h = sb2[h];
            #pragma unroll
            for (int jj = 0; jj < 12; ++jj) {
                float v = sb1[jj];
                if (qrow == kj) v += sw1[0][jj];
                v += xp[0][j] * sw1[1][jj];
                v += xp[1][j] * sw1[2][jj];
                v += xp[2][j] * sw1[3][jj];
                v += xp[3][j] * sw1[4][jj];
                v += xp[4][j] * sw1[5][jj];
                v = fmaxf(v, 0.f);
                bias_h = fmaf(v, sw2[jj][h], bias_h);
            }
            float sv = s4[j] * 0.125f + bias_h;
            if (mask[(long)b * Nn + kj] == 0) sv = -1e9f;
            sc[qi][kjb + j] = sv;
        }
        __syncthreads();
    }

    // ------------------ pass 2: softmax + weight accumulation ------------------
    {
        const int r = tid >> 4;     // row 0..15
        const int c = tid & 15;     // 16 lanes per row
        float mx = -INFINITY;
        #pragma unroll
        for (int i = 0; i < 32; ++i) mx = fmaxf(mx, sc[r][c + 16 * i]);
        #pragma unroll
        for (int o = 1; o < 16; o <<= 1) mx = fmaxf(mx, __shfl_xor(mx, o));

        float vals[32];
        float sum = 0.f;
        #pragma unroll
        for (int i = 0; i < 32; ++i) {
            vals[i] = expf(sc[r][c + 16 * i] - mx);
            sum += vals[i];
        }
        #pragma unroll
        for (int o = 1; o < 16; o <<= 1) sum += __shfl_xor(sum, o);
        const float inv = 1.f / sum;

        float* wrow = wout + ((long)b * Nn + q0 + r) * Nn;
        #pragma unroll
        for (int i = 0; i < 32; ++i) {
            const float p = vals[i] * inv;
            sc[r][c + 16 * i] = p;
            atomicAdd(&wrow[c + 16 * i], p * 0.125f);
        }
    }
    __syncthreads();

    // ------------------ pass 3: ctx = attn @ V ------------------
    const int dg = tid >> 4;        // d group (4 floats)
    float c4[4] = {0.f, 0.f, 0.f, 0.f};
    for (int kt = 0; kt < 8; ++kt) {
        #pragma unroll
        for (int i = 0; i < 4; ++i) {
            const int kk = (tid >> 4) + i * 16;
            const int d4 = (tid & 15) * 4;
            *(float4*)&kv[kk][d4] =
                *(const float4*)&qkv[((long)b * Nn + kt * 64 + kk) * (3 * Dd)
                                     + 2 * Dd + h * HD + d4];
        }
        __syncthreads();

        #pragma unroll
        for (int kk = 0; kk < 64; kk += 4) {
            float4 p4 = *(const float4*)&sc[qi][kt * 64 + kk];
            float pa[4]; *(float4*)pa = p4;
            #pragma unroll
            for (int u = 0; u < 4; ++u) {
                float4 v4 = *(const float4*)&kv[kk + u][dg * 4];
                c4[0] = fmaf(pa[u], v4.x, c4[0]);
                c4[1] = fmaf(pa[u], v4.y, c4[1]);
                c4[2] = fmaf(pa[u], v4.z, c4[2]);
                c4[3] = fmaf(pa[u], v4.w, c4[3]);
            }
        }
        __syncthreads();
    }
    {
        float4 o; o.x = c4[0]; o.y = c4[1]; o.z = c4[2]; o.w = c4[3];
        *(float4*)&ctx[((long)b * Nn + qrow) * Dd + h * HD + dg * 4] = o;
    }
}

// ---------------------------------------------------------------------------
extern "C" void kernel_launch(void* const* d_in, const int* in_sizes, int n_in,
                              void* d_out, int out_size, void* d_ws, size_t ws_size,
                              hipStream_t stream)
{
    const float* h_in      = (const float*)d_in[0];
    const float* adj       = (const float*)d_in[1];
    const int*   mask      = (const int*)d_in[2];
    const float* in_proj_w = (const float*)d_in[3];
    const float* in_proj_b = (const float*)d_in[4];
    const float* out_w     = (const float*)d_in[5];
    const float* out_b     = (const float*)d_in[6];
    const float* ffn_w1    = (const float*)d_in[7];
    const float* ffn_b1    = (const float*)d_in[8];
    const float* ffn_w2    = (const float*)d_in[9];
    const float* ffn_b2    = (const float*)d_in[10];

    const long NN  = (long)Nn * Nn;          // 262144
    const long BNN = (long)Bz * NN;          // 4194304

    float* ws     = (float*)d_ws;
    float* powers = ws;                       // 5 * BNN   (P^1..P^5)
    float* qkv    = ws + 5 * BNN;             // Bz*Nn*3*Dd
    float* ctxb   = qkv + (long)Bz * Nn * 3 * Dd;  // Bz*Nn*Dd

    float* out_atten = (float*)d_out;         // [B][N][D]
    float* out_wts   = out_atten + BNN;       // [B][N][N]

    // weights output is accumulated atomically -> zero it
    hipMemsetAsync(out_wts, 0, BNN * sizeof(float), stream);

    // P^1
    computeP<<<dim3(Nn, Bz), 64, 0, stream>>>(adj, mask, powers);

    // P^2..P^5  (pw = pw @ P)
    for (int s = 1; s < 5; ++s) {
        gemm128<false, false><<<dim3(4, 4, Bz), 256, 0, stream>>>(
            powers + (long)(s - 1) * BNN, powers, nullptr, powers + (long)s * BNN,
            Nn, Nn, Nn, NN, NN, NN);
    }

    // qkv = h @ in_proj_w^T + in_proj_b   -> [B][N][3D]
    gemm128<true, true><<<dim3(12, 4, Bz), 256, 0, stream>>>(
        h_in, in_proj_w, in_proj_b, qkv,
        Nn, 3 * Dd, Dd, (long)Nn * Dd, 0, (long)Nn * 3 * Dd);

    // attention (fills ctxb and accumulates out_wts)
    attn_kernel<<<dim3(Nn / TQ, Hh, Bz), 256, 0, stream>>>(
        qkv, powers, mask, ffn_w1, ffn_b1, ffn_w2, ffn_b2, ctxb, out_wts);

    // atten_out = ctx @ out_w^T + out_b
    gemm128<true, true><<<dim3(4, 4, Bz), 256, 0, stream>>>(
        ctxb, out_w, out_b, out_atten,
        Nn, Dd, Dd, (long)Nn * Dd, 0, (long)Nn * Dd);
}

// Round 3
// 1190.798 us; speedup vs baseline: 1.3111x; 1.3111x over previous
//
#include <hip/hip_runtime.h>
#include <hip/hip_bf16.h>

#define Bz 16
#define Nn 512
#define Dd 512
#define Hh 8
#define HD 64

static const long NNl  = (long)Nn * Nn;        // 262144
static const long BNNl = (long)Bz * Nn * Nn;   // 4194304

__device__ inline float bf2f(unsigned short u) {
    unsigned int x = ((unsigned int)u) << 16;
    return __uint_as_float(x);
}
__device__ inline unsigned short f2bf(float f) {
    __hip_bfloat16 h = __float2bfloat16(f);
    return *reinterpret_cast<unsigned short*>(&h);
}

// ---------------------------------------------------------------------------
// Kernel 1: P = row-normalized masked adjacency. One wave per (b, row).
// ---------------------------------------------------------------------------
__global__ __launch_bounds__(64)
void computeP(const float* __restrict__ adj, const int* __restrict__ mask,
              float* __restrict__ P)
{
    const int i = blockIdx.x;
    const int b = blockIdx.y;
    const int lane = threadIdx.x;
    const float* arow = adj + ((long)b * Nn + i) * Nn;
    const int*   mrow = mask + (long)b * Nn;
    const bool mi = (mrow[i] != 0);

    float vals[8];
    float s = 0.f;
    #pragma unroll
    for (int t = 0; t < 2; ++t) {
        const int c = lane * 4 + t * 256;
        float4 a4 = *(const float4*)&arow[c];
        int4   m4 = *(const int4*)&mrow[c];
        float v0 = (mi && m4.x) ? a4.x : 0.f;
        float v1 = (mi && m4.y) ? a4.y : 0.f;
        float v2 = (mi && m4.z) ? a4.z : 0.f;
        float v3 = (mi && m4.w) ? a4.w : 0.f;
        vals[t*4+0] = v0; vals[t*4+1] = v1; vals[t*4+2] = v2; vals[t*4+3] = v3;
        s += v0 + v1 + v2 + v3;
    }
    #pragma unroll
    for (int o = 1; o < 64; o <<= 1) s += __shfl_xor(s, o);
    const float den = (s == 0.f) ? 1.f : s;

    float* prow = P + ((long)b * Nn + i) * Nn;
    #pragma unroll
    for (int t = 0; t < 2; ++t) {
        const int c = lane * 4 + t * 256;
        float4 o4;
        o4.x = vals[t*4+0] / den;
        o4.y = vals[t*4+1] / den;
        o4.z = vals[t*4+2] / den;
        o4.w = vals[t*4+3] / den;
        *(float4*)&prow[c] = o4;
    }
}

// ---------------------------------------------------------------------------
// Kernel 2: batched fp32 GEMM (unchanged, proven).
// ---------------------------------------------------------------------------
template<bool BT, bool BIAS>
__global__ __launch_bounds__(256)
void gemm128(const float* __restrict__ A, const float* __restrict__ Bm,
             const float* __restrict__ bias, float* __restrict__ C,
             int M, int N, int K, long sA, long sB, long sC)
{
    __shared__ float As[16][128];
    __shared__ float Bs[16][128];

    const int bz = blockIdx.z;
    A  += (long)bz * sA;
    Bm += (long)bz * sB;
    C  += (long)bz * sC;
    const int bm = blockIdx.y * 128;
    const int bn = blockIdx.x * 128;
    const int tid = threadIdx.x;
    const int tx = tid & 15;
    const int ty = tid >> 4;

    float acc[8][8];
    #pragma unroll
    for (int i = 0; i < 8; ++i)
        #pragma unroll
        for (int j = 0; j < 8; ++j) acc[i][j] = 0.f;

    for (int k0 = 0; k0 < K; k0 += 16) {
        #pragma unroll
        for (int i = 0; i < 2; ++i) {
            const int r = (tid >> 2) + i * 64;
            const int c = (tid & 3) * 4;
            float4 a4 = *(const float4*)&A[(long)(bm + r) * K + k0 + c];
            As[c+0][r] = a4.x; As[c+1][r] = a4.y;
            As[c+2][r] = a4.z; As[c+3][r] = a4.w;
        }
        if (!BT) {
            #pragma unroll
            for (int i = 0; i < 2; ++i) {
                const int kk = (tid >> 5) + i * 8;
                const int c  = (tid & 31) * 4;
                *(float4*)&Bs[kk][c] =
                    *(const float4*)&Bm[(long)(k0 + kk) * N + bn + c];
            }
        } else {
            #pragma unroll
            for (int i = 0; i < 2; ++i) {
                const int cc = (tid >> 2) + i * 64;
                const int kk = (tid & 3) * 4;
                float4 b4 = *(const float4*)&Bm[(long)(bn + cc) * K + k0 + kk];
                Bs[kk+0][cc] = b4.x; Bs[kk+1][cc] = b4.y;
                Bs[kk+2][cc] = b4.z; Bs[kk+3][cc] = b4.w;
            }
        }
        __syncthreads();

        #pragma unroll
        for (int kk = 0; kk < 16; ++kk) {
            float a[8], bb[8];
            *(float4*)&a[0]  = *(const float4*)&As[kk][ty*4];
            *(float4*)&a[4]  = *(const float4*)&As[kk][64 + ty*4];
            *(float4*)&bb[0] = *(const float4*)&Bs[kk][tx*4];
            *(float4*)&bb[4] = *(const float4*)&Bs[kk][64 + tx*4];
            #pragma unroll
            for (int i = 0; i < 8; ++i)
                #pragma unroll
                for (int j = 0; j < 8; ++j)
                    acc[i][j] = fmaf(a[i], bb[j], acc[i][j]);
        }
        __syncthreads();
    }

    float bv[8];
    if (BIAS) {
        *(float4*)&bv[0] = *(const float4*)&bias[bn + tx*4];
        *(float4*)&bv[4] = *(const float4*)&bias[bn + 64 + tx*4];
    }
    #pragma unroll
    for (int i = 0; i < 8; ++i) {
        const int r = bm + ((i < 4) ? (ty*4 + i) : (64 + ty*4 + (i - 4)));
        float o0[4], o1[4];
        #pragma unroll
        for (int j = 0; j < 4; ++j) {
            o0[j] = acc[i][j]     + (BIAS ? bv[j]     : 0.f);
            o1[j] = acc[i][j + 4] + (BIAS ? bv[j + 4] : 0.f);
        }
        *(float4*)&C[(long)r * N + bn + tx*4]      = *(float4*)o0;
        *(float4*)&C[(long)r * N + bn + 64 + tx*4] = *(float4*)o1;
    }
}

// ---------------------------------------------------------------------------
// Kernel 3: precompute edge-FFN bias -> [B][H][N][N] (fp32 or bf16).
// Block: 2 q-rows x 512 keys; thread: 4 keys.
// ---------------------------------------------------------------------------
template<bool BF16OUT>
__global__ __launch_bounds__(256)
void bias_ffn(const float* __restrict__ powers,
              const float* __restrict__ w1, const float* __restrict__ b1,
              const float* __restrict__ w2, const float* __restrict__ b2,
              void* __restrict__ biasOut)
{
    __shared__ float sw1[6][12], sb1[12], sw2[12][8], sb2[8];
    const int tid = threadIdx.x;
    if (tid < 72)        sw1[tid/12][tid%12] = w1[tid];
    else if (tid < 84)   sb1[tid-72] = b1[tid-72];
    else if (tid < 180)  sw2[(tid-84)/8][(tid-84)%8] = w2[tid-84];
    else if (tid < 188)  sb2[tid-180] = b2[tid-180];
    __syncthreads();

    const int b = blockIdx.y;
    const int ql = tid >> 7;                    // 0..1
    const int qrow = blockIdx.x * 2 + ql;
    const int kk = (tid & 127) * 4;

    float xp[5][4];
    #pragma unroll
    for (int s = 0; s < 5; ++s) {
        float4 t = *(const float4*)&powers[((long)(s*Bz+b))*NNl + (long)qrow*Nn + kk];
        xp[s][0]=t.x; xp[s][1]=t.y; xp[s][2]=t.z; xp[s][3]=t.w;
    }
    float outh[8][4];
    #pragma unroll
    for (int j = 0; j < 4; ++j) {
        float hid[12];
        #pragma unroll
        for (int jj = 0; jj < 12; ++jj) {
            float v = sb1[jj];
            if (qrow == kk + j) v += sw1[0][jj];
            v = fmaf(xp[0][j], sw1[1][jj], v);
            v = fmaf(xp[1][j], sw1[2][jj], v);
            v = fmaf(xp[2][j], sw1[3][jj], v);
            v = fmaf(xp[3][j], sw1[4][jj], v);
            v = fmaf(xp[4][j], sw1[5][jj], v);
            hid[jj] = fmaxf(v, 0.f);
        }
        #pragma unroll
        for (int h = 0; h < 8; ++h) {
            float a = sb2[h];
            #pragma unroll
            for (int jj = 0; jj < 12; ++jj) a = fmaf(hid[jj], sw2[jj][h], a);
            outh[h][j] = a;
        }
    }
    #pragma unroll
    for (int h = 0; h < 8; ++h) {
        const long off = ((long)(b*Hh+h))*NNl + (long)qrow*Nn + kk;
        if (BF16OUT) {
            ushort4 u;
            u.x = f2bf(outh[h][0]); u.y = f2bf(outh[h][1]);
            u.z = f2bf(outh[h][2]); u.w = f2bf(outh[h][3]);
            *(ushort4*)((unsigned short*)biasOut + off) = u;
        } else {
            float4 o = {outh[h][0], outh[h][1], outh[h][2], outh[h][3]};
            *(float4*)((float*)biasOut + off) = o;
        }
    }
}

// ---------------------------------------------------------------------------
// Kernel 4: attention. Block = (b, 16-row q-tile), loops over all 8 heads.
//   - Q row held in registers (64 VGPR), K/V staged in LDS
//   - scores stored transposed scT[key][q] (stride 17: conflict-free b32)
//   - softmax: probs kept in registers; head-mean accumulated in registers
//     -> ONE coalesced wout write per block, NO atomics, NO memset
//   - PV: 4q x 4d register tile, 4-way k-split + LDS tree reduce
// ---------------------------------------------------------------------------
template<bool BF16B>
__global__ __launch_bounds__(256)
void attn2(const float* __restrict__ qkv, const void* __restrict__ biasT,
           const int* __restrict__ mask,
           float* __restrict__ ctx, float* __restrict__ wout)
{
    __shared__ float scT[512][17];    // 34816 B: scores^T [key][q]
    __shared__ float kvs[64][68];     // 17408 B: K/V tile + reduce scratch

    const int qt = blockIdx.x, b = blockIdx.y;
    const int q0 = qt * 16;
    const int tid = threadIdx.x;

    const int qi = tid >> 4;          // pass1/pass2 q-row 0..15
    const int kg = tid & 15;          // pass1 key group (4 keys)
    // pass3 roles
    const int kq = tid >> 6;          // 0..3 (wave id -> k split)
    const int qg = (tid >> 4) & 3;    // 0..3 (4 q rows)
    const int dg = tid & 15;          // 0..15 (4 dims)

    float wacc[32];
    #pragma unroll
    for (int i = 0; i < 32; ++i) wacc[i] = 0.f;

    for (int h = 0; h < Hh; ++h) {
        // ---- Q row -> registers (16 lanes share a row; L1/L2 dedups) ----
        float4 qreg[16];
        {
            const float* qp = qkv + ((long)b*Nn + q0 + qi)*(3*Dd) + h*HD;
            #pragma unroll
            for (int t = 0; t < 16; ++t) qreg[t] = *(const float4*)&qp[t*4];
        }

        // ------------------ pass 1: scores -> scT ------------------
        for (int kt = 0; kt < 8; ++kt) {
            {   // stage K tile [64][64]
                const int row  = tid >> 2;
                const int doff = (tid & 3) * 16;
                const float* kp = qkv + ((long)b*Nn + kt*64 + row)*(3*Dd)
                                  + Dd + h*HD + doff;
                #pragma unroll
                for (int t = 0; t < 4; ++t)
                    *(float4*)&kvs[row][doff + t*4] = *(const float4*)&kp[t*4];
            }
            __syncthreads();

            const int kbase = kt*64 + kg*4;
            const int4 m4 = *(const int4*)&mask[(long)b*Nn + kbase];
            float bias4[4];
            if (BF16B) {
                ushort4 u = *(const ushort4*)((const unsigned short*)biasT
                            + ((long)(b*Hh+h))*NNl + (long)(q0+qi)*Nn + kbase);
                bias4[0] = bf2f(u.x); bias4[1] = bf2f(u.y);
                bias4[2] = bf2f(u.z); bias4[3] = bf2f(u.w);
            } else {
                float4 f = *(const float4*)((const float*)biasT
                            + ((long)(b*Hh+h))*NNl + (long)(q0+qi)*Nn + kbase);
                bias4[0]=f.x; bias4[1]=f.y; bias4[2]=f.z; bias4[3]=f.w;
            }
            const int mm[4] = {m4.x, m4.y, m4.z, m4.w};
            #pragma unroll
            for (int j = 0; j < 4; ++j) {
                const float* krow = &kvs[kg*4 + j][0];
                float s = 0.f;
                #pragma unroll
                for (int d4 = 0; d4 < 16; ++d4) {
                    float4 k4 = *(const float4*)&krow[d4*4];
                    s += qreg[d4].x*k4.x + qreg[d4].y*k4.y
                       + qreg[d4].z*k4.z + qreg[d4].w*k4.w;
                }
                float sv = s * 0.125f + bias4[j];
                if (!mm[j]) sv = -1e9f;
                scT[kbase + j][qi] = sv;
            }
            __syncthreads();
        }

        // ------------------ pass 2: softmax (probs stay in regs) ------------------
        {
            const int c = kg;      // 16 lanes per row
            float pv[32];
            float mx = -INFINITY;
            #pragma unroll
            for (int i = 0; i < 32; ++i) {
                pv[i] = scT[c + 16*i][qi];
                mx = fmaxf(mx, pv[i]);
            }
            #pragma unroll
            for (int o = 1; o < 16; o <<= 1) mx = fmaxf(mx, __shfl_xor(mx, o));
            float sum = 0.f;
            #pragma unroll
            for (int i = 0; i < 32; ++i) { pv[i] = expf(pv[i] - mx); sum += pv[i]; }
            #pragma unroll
            for (int o = 1; o < 16; o <<= 1) sum += __shfl_xor(sum, o);
            const float inv = 1.f / sum;
            #pragma unroll
            for (int i = 0; i < 32; ++i) {
                const float p = pv[i] * inv;
                scT[c + 16*i][qi] = p;
                wacc[i] += p;
            }
        }
        __syncthreads();

        // ------------------ pass 3: ctx = P @ V ------------------
        float4 acc[4];
        #pragma unroll
        for (int i = 0; i < 4; ++i) acc[i] = make_float4(0.f, 0.f, 0.f, 0.f);

        for (int kt = 0; kt < 8; ++kt) {
            {   // stage V tile
                const int row  = tid >> 2;
                const int doff = (tid & 3) * 16;
                const float* vp = qkv + ((long)b*Nn + kt*64 + row)*(3*Dd)
                                  + 2*Dd + h*HD + doff;
                #pragma unroll
                for (int t = 0; t < 4; ++t)
                    *(float4*)&kvs[row][doff + t*4] = *(const float4*)&vp[t*4];
            }
            __syncthreads();

            #pragma unroll
            for (int kk2 = 0; kk2 < 16; ++kk2) {
                const int kl = kq*16 + kk2;           // local key in tile
                const int k  = kt*64 + kl;            // global key
                float p0 = scT[k][qg*4+0];
                float p1 = scT[k][qg*4+1];
                float p2 = scT[k][qg*4+2];
                float p3 = scT[k][qg*4+3];
                float4 v4 = *(const float4*)&kvs[kl][dg*4];
                acc[0].x = fmaf(p0, v4.x, acc[0].x); acc[0].y = fmaf(p0, v4.y, acc[0].y);
                acc[0].z = fmaf(p0, v4.z, acc[0].z); acc[0].w = fmaf(p0, v4.w, acc[0].w);
                acc[1].x = fmaf(p1, v4.x, acc[1].x); acc[1].y = fmaf(p1, v4.y, acc[1].y);
                acc[1].z = fmaf(p1, v4.z, acc[1].z); acc[1].w = fmaf(p1, v4.w, acc[1].w);
                acc[2].x = fmaf(p2, v4.x, acc[2].x); acc[2].y = fmaf(p2, v4.y, acc[2].y);
                acc[2].z = fmaf(p2, v4.z, acc[2].z); acc[2].w = fmaf(p2, v4.w, acc[2].w);
                acc[3].x = fmaf(p3, v4.x, acc[3].x); acc[3].y = fmaf(p3, v4.y, acc[3].y);
                acc[3].z = fmaf(p3, v4.z, acc[3].z); acc[3].w = fmaf(p3, v4.w, acc[3].w);
            }
            __syncthreads();
        }

        // k-split reduce via LDS scratch (kvs free now): 3*64*16 = 3072 floats
        if (kq > 0) {
            float* dst = &kvs[0][0] + ((long)(kq-1)*64 + (qg*16 + dg)) * 16;
            #pragma unroll
            for (int i = 0; i < 4; ++i) *(float4*)&dst[i*4] = acc[i];
        }
        __syncthreads();
        if (kq == 0) {
            #pragma unroll
            for (int k2 = 0; k2 < 3; ++k2) {
                const float* src = &kvs[0][0] + ((long)k2*64 + (qg*16 + dg)) * 16;
                #pragma unroll
                for (int i = 0; i < 4; ++i) {
                    float4 t = *(const float4*)&src[i*4];
                    acc[i].x += t.x; acc[i].y += t.y; acc[i].z += t.z; acc[i].w += t.w;
                }
            }
            #pragma unroll
            for (int i = 0; i < 4; ++i)
                *(float4*)&ctx[((long)b*Nn + q0 + qg*4 + i)*Dd + h*HD + dg*4] = acc[i];
        }
        __syncthreads();
    }

    // ---- head-averaged attention weights: single coalesced write ----
    {
        float* wrow = wout + ((long)b*Nn + q0 + qi) * Nn;
        #pragma unroll
        for (int i = 0; i < 32; ++i) wrow[kg + 16*i] = wacc[i] * 0.125f;
    }
}

// ---------------------------------------------------------------------------
extern "C" void kernel_launch(void* const* d_in, const int* in_sizes, int n_in,
                              void* d_out, int out_size, void* d_ws, size_t ws_size,
                              hipStream_t stream)
{
    const float* h_in      = (const float*)d_in[0];
    const float* adj       = (const float*)d_in[1];
    const int*   mask      = (const int*)d_in[2];
    const float* in_proj_w = (const float*)d_in[3];
    const float* in_proj_b = (const float*)d_in[4];
    const float* out_w     = (const float*)d_in[5];
    const float* out_b     = (const float*)d_in[6];
    const float* ffn_w1    = (const float*)d_in[7];
    const float* ffn_b1    = (const float*)d_in[8];
    const float* ffn_w2    = (const float*)d_in[9];
    const float* ffn_b2    = (const float*)d_in[10];

    float* ws = (float*)d_ws;

    // Region layout (bytes):
    //   [0, 83886080)              : powers P^1..P^5 (5*BNN fp32)  -- dead after bias_ffn
    //   [0, 50331648)              : qkv (overlays powers AFTER bias_ffn)
    //   [50331648, 67108864)       : ctx
    //   [83886080, ...)            : bias  fp32 (134 MB) or bf16 (67 MB)
    float* powers = ws;
    float* qkv    = ws;
    float* ctxb   = ws + 12582912;                // 50331648 B / 4
    void*  biasT  = (void*)((char*)d_ws + 83886080);

    const bool fp32bias = (ws_size >= 218103808ull);   // else bf16: exactly 151 MB total

    float* out_atten = (float*)d_out;             // [B][N][D]
    float* out_wts   = out_atten + BNNl;          // [B][N][N]

    // P^1
    computeP<<<dim3(Nn, Bz), 64, 0, stream>>>(adj, mask, powers);

    // P^2..P^5
    for (int s = 1; s < 5; ++s) {
        gemm128<false, false><<<dim3(4, 4, Bz), 256, 0, stream>>>(
            powers + (long)(s-1)*BNNl, powers, nullptr, powers + (long)s*BNNl,
            Nn, Nn, Nn, NNl, NNl, NNl);
    }

    // edge-FFN bias (consumes powers; after this, powers region is reusable)
    if (fp32bias)
        bias_ffn<false><<<dim3(Nn/2, Bz), 256, 0, stream>>>(
            powers, ffn_w1, ffn_b1, ffn_w2, ffn_b2, biasT);
    else
        bias_ffn<true><<<dim3(Nn/2, Bz), 256, 0, stream>>>(
            powers, ffn_w1, ffn_b1, ffn_w2, ffn_b2, biasT);

    // qkv = h @ in_proj_w^T + b   (writes over dead powers region)
    gemm128<true, true><<<dim3(12, 4, Bz), 256, 0, stream>>>(
        h_in, in_proj_w, in_proj_b, qkv,
        Nn, 3*Dd, Dd, (long)Nn*Dd, 0, (long)Nn*3*Dd);

    // attention
    if (fp32bias)
        attn2<false><<<dim3(Nn/16, Bz), 256, 0, stream>>>(qkv, biasT, mask, ctxb, out_wts);
    else
        attn2<true><<<dim3(Nn/16, Bz), 256, 0, stream>>>(qkv, biasT, mask, ctxb, out_wts);

    // atten_out = ctx @ out_w^T + out_b
    gemm128<true, true><<<dim3(4, 4, Bz), 256, 0, stream>>>(
        ctxb, out_w, out_b, out_atten,
        Nn, Dd, Dd, (long)Nn*Dd, 0, (long)Nn*Dd);
}

// Round 4
// 961.245 us; speedup vs baseline: 1.6242x; 1.2388x over previous
//
#include <hip/hip_runtime.h>
#include <hip/hip_bf16.h>

#define Bz 16
#define Nn 512
#define Dd 512
#define Hh 8
#define HD 64

static const long NNl  = (long)Nn * Nn;        // 262144
static const long BNNl = (long)Bz * Nn * Nn;   // 4194304

__device__ inline float bf2f(unsigned short u) {
    unsigned int x = ((unsigned int)u) << 16;
    return __uint_as_float(x);
}
__device__ inline unsigned short f2bf(float f) {
    __hip_bfloat16 h = __float2bfloat16(f);
    return *reinterpret_cast<unsigned short*>(&h);
}

// ---------------------------------------------------------------------------
// Kernel 1: P = row-normalized masked adjacency. One wave per (b, row).
// ---------------------------------------------------------------------------
__global__ __launch_bounds__(64)
void computeP(const float* __restrict__ adj, const int* __restrict__ mask,
              float* __restrict__ P)
{
    const int i = blockIdx.x;
    const int b = blockIdx.y;
    const int lane = threadIdx.x;
    const float* arow = adj + ((long)b * Nn + i) * Nn;
    const int*   mrow = mask + (long)b * Nn;
    const bool mi = (mrow[i] != 0);

    float vals[8];
    float s = 0.f;
    #pragma unroll
    for (int t = 0; t < 2; ++t) {
        const int c = lane * 4 + t * 256;
        float4 a4 = *(const float4*)&arow[c];
        int4   m4 = *(const int4*)&mrow[c];
        float v0 = (mi && m4.x) ? a4.x : 0.f;
        float v1 = (mi && m4.y) ? a4.y : 0.f;
        float v2 = (mi && m4.z) ? a4.z : 0.f;
        float v3 = (mi && m4.w) ? a4.w : 0.f;
        vals[t*4+0] = v0; vals[t*4+1] = v1; vals[t*4+2] = v2; vals[t*4+3] = v3;
        s += v0 + v1 + v2 + v3;
    }
    #pragma unroll
    for (int o = 1; o < 64; o <<= 1) s += __shfl_xor(s, o);
    const float den = (s == 0.f) ? 1.f : s;

    float* prow = P + ((long)b * Nn + i) * Nn;
    #pragma unroll
    for (int t = 0; t < 2; ++t) {
        const int c = lane * 4 + t * 256;
        float4 o4;
        o4.x = vals[t*4+0] / den;
        o4.y = vals[t*4+1] / den;
        o4.z = vals[t*4+2] / den;
        o4.w = vals[t*4+3] / den;
        *(float4*)&prow[c] = o4;
    }
}

// ---------------------------------------------------------------------------
// Kernel 2a: batched fp32 GEMM, 128x128 tile (proven; used for qkv: 3 blk/CU)
// ---------------------------------------------------------------------------
template<bool BT, bool BIAS>
__global__ __launch_bounds__(256)
void gemm128(const float* __restrict__ A, const float* __restrict__ Bm,
             const float* __restrict__ bias, float* __restrict__ C,
             int M, int N, int K, long sA, long sB, long sC)
{
    __shared__ float As[16][128];
    __shared__ float Bs[16][128];

    const int bz = blockIdx.z;
    A  += (long)bz * sA;
    Bm += (long)bz * sB;
    C  += (long)bz * sC;
    const int bm = blockIdx.y * 128;
    const int bn = blockIdx.x * 128;
    const int tid = threadIdx.x;
    const int tx = tid & 15;
    const int ty = tid >> 4;

    float acc[8][8];
    #pragma unroll
    for (int i = 0; i < 8; ++i)
        #pragma unroll
        for (int j = 0; j < 8; ++j) acc[i][j] = 0.f;

    for (int k0 = 0; k0 < K; k0 += 16) {
        #pragma unroll
        for (int i = 0; i < 2; ++i) {
            const int r = (tid >> 2) + i * 64;
            const int c = (tid & 3) * 4;
            float4 a4 = *(const float4*)&A[(long)(bm + r) * K + k0 + c];
            As[c+0][r] = a4.x; As[c+1][r] = a4.y;
            As[c+2][r] = a4.z; As[c+3][r] = a4.w;
        }
        if (!BT) {
            #pragma unroll
            for (int i = 0; i < 2; ++i) {
                const int kk = (tid >> 5) + i * 8;
                const int c  = (tid & 31) * 4;
                *(float4*)&Bs[kk][c] =
                    *(const float4*)&Bm[(long)(k0 + kk) * N + bn + c];
            }
        } else {
            #pragma unroll
            for (int i = 0; i < 2; ++i) {
                const int cc = (tid >> 2) + i * 64;
                const int kk = (tid & 3) * 4;
                float4 b4 = *(const float4*)&Bm[(long)(bn + cc) * K + k0 + kk];
                Bs[kk+0][cc] = b4.x; Bs[kk+1][cc] = b4.y;
                Bs[kk+2][cc] = b4.z; Bs[kk+3][cc] = b4.w;
            }
        }
        __syncthreads();

        #pragma unroll
        for (int kk = 0; kk < 16; ++kk) {
            float a[8], bb[8];
            *(float4*)&a[0]  = *(const float4*)&As[kk][ty*4];
            *(float4*)&a[4]  = *(const float4*)&As[kk][64 + ty*4];
            *(float4*)&bb[0] = *(const float4*)&Bs[kk][tx*4];
            *(float4*)&bb[4] = *(const float4*)&Bs[kk][64 + tx*4];
            #pragma unroll
            for (int i = 0; i < 8; ++i)
                #pragma unroll
                for (int j = 0; j < 8; ++j)
                    acc[i][j] = fmaf(a[i], bb[j], acc[i][j]);
        }
        __syncthreads();
    }

    float bv[8];
    if (BIAS) {
        *(float4*)&bv[0] = *(const float4*)&bias[bn + tx*4];
        *(float4*)&bv[4] = *(const float4*)&bias[bn + 64 + tx*4];
    }
    #pragma unroll
    for (int i = 0; i < 8; ++i) {
        const int r = bm + ((i < 4) ? (ty*4 + i) : (64 + ty*4 + (i - 4)));
        float o0[4], o1[4];
        #pragma unroll
        for (int j = 0; j < 4; ++j) {
            o0[j] = acc[i][j]     + (BIAS ? bv[j]     : 0.f);
            o1[j] = acc[i][j + 4] + (BIAS ? bv[j + 4] : 0.f);
        }
        *(float4*)&C[(long)r * N + bn + tx*4]      = *(float4*)o0;
        *(float4*)&C[(long)r * N + bn + 64 + tx*4] = *(float4*)o1;
    }
}

// ---------------------------------------------------------------------------
// Kernel 2b: 128x64-tile GEMM (2 blocks/CU at 512-wide problems; powers+out).
// 8x4 micro-tile per thread.
// ---------------------------------------------------------------------------
template<bool BT, bool BIAS>
__global__ __launch_bounds__(256)
void gemm64(const float* __restrict__ A, const float* __restrict__ Bm,
            const float* __restrict__ bias, float* __restrict__ C,
            int M, int N, int K, long sA, long sB, long sC)
{
    __shared__ float As[16][128];
    __shared__ float Bs[16][64];

    const int bz = blockIdx.z;
    A  += (long)bz * sA;
    Bm += (long)bz * sB;
    C  += (long)bz * sC;
    const int bm = blockIdx.y * 128;
    const int bn = blockIdx.x * 64;
    const int tid = threadIdx.x;
    const int tx = tid & 15;
    const int ty = tid >> 4;

    float acc[8][4];
    #pragma unroll
    for (int i = 0; i < 8; ++i)
        #pragma unroll
        for (int j = 0; j < 4; ++j) acc[i][j] = 0.f;

    for (int k0 = 0; k0 < K; k0 += 16) {
        #pragma unroll
        for (int i = 0; i < 2; ++i) {
            const int r = (tid >> 2) + i * 64;
            const int c = (tid & 3) * 4;
            float4 a4 = *(const float4*)&A[(long)(bm + r) * K + k0 + c];
            As[c+0][r] = a4.x; As[c+1][r] = a4.y;
            As[c+2][r] = a4.z; As[c+3][r] = a4.w;
        }
        if (!BT) {
            const int kk = tid >> 4;            // 0..15
            const int c  = (tid & 15) * 4;
            *(float4*)&Bs[kk][c] =
                *(const float4*)&Bm[(long)(k0 + kk) * N + bn + c];
        } else {
            const int cc = tid >> 2;            // 0..63
            const int kk = (tid & 3) * 4;
            float4 b4 = *(const float4*)&Bm[(long)(bn + cc) * K + k0 + kk];
            Bs[kk+0][cc] = b4.x; Bs[kk+1][cc] = b4.y;
            Bs[kk+2][cc] = b4.z; Bs[kk+3][cc] = b4.w;
        }
        __syncthreads();

        #pragma unroll
        for (int kk = 0; kk < 16; ++kk) {
            float a[8], bb[4];
            *(float4*)&a[0]  = *(const float4*)&As[kk][ty*4];
            *(float4*)&a[4]  = *(const float4*)&As[kk][64 + ty*4];
            *(float4*)&bb[0] = *(const float4*)&Bs[kk][tx*4];
            #pragma unroll
            for (int i = 0; i < 8; ++i)
                #pragma unroll
                for (int j = 0; j < 4; ++j)
                    acc[i][j] = fmaf(a[i], bb[j], acc[i][j]);
        }
        __syncthreads();
    }

    float bv[4];
    if (BIAS) *(float4*)&bv[0] = *(const float4*)&bias[bn + tx*4];
    #pragma unroll
    for (int i = 0; i < 8; ++i) {
        const int r = bm + ((i < 4) ? (ty*4 + i) : (64 + ty*4 + (i - 4)));
        float o0[4];
        #pragma unroll
        for (int j = 0; j < 4; ++j)
            o0[j] = acc[i][j] + (BIAS ? bv[j] : 0.f);
        *(float4*)&C[(long)r * N + bn + tx*4] = *(float4*)o0;
    }
}

// ---------------------------------------------------------------------------
// Kernel 3: precompute edge-FFN bias -> [B][H][N][N] (fp32 or bf16).
// ---------------------------------------------------------------------------
template<bool BF16OUT>
__global__ __launch_bounds__(256)
void bias_ffn(const float* __restrict__ powers,
              const float* __restrict__ w1, const float* __restrict__ b1,
              const float* __restrict__ w2, const float* __restrict__ b2,
              void* __restrict__ biasOut)
{
    __shared__ float sw1[6][12], sb1[12], sw2[12][8], sb2[8];
    const int tid = threadIdx.x;
    if (tid < 72)        sw1[tid/12][tid%12] = w1[tid];
    else if (tid < 84)   sb1[tid-72] = b1[tid-72];
    else if (tid < 180)  sw2[(tid-84)/8][(tid-84)%8] = w2[tid-84];
    else if (tid < 188)  sb2[tid-180] = b2[tid-180];
    __syncthreads();

    const int b = blockIdx.y;
    const int ql = tid >> 7;                    // 0..1
    const int qrow = blockIdx.x * 2 + ql;
    const int kk = (tid & 127) * 4;

    float xp[5][4];
    #pragma unroll
    for (int s = 0; s < 5; ++s) {
        float4 t = *(const float4*)&powers[((long)(s*Bz+b))*NNl + (long)qrow*Nn + kk];
        xp[s][0]=t.x; xp[s][1]=t.y; xp[s][2]=t.z; xp[s][3]=t.w;
    }
    float outh[8][4];
    #pragma unroll
    for (int j = 0; j < 4; ++j) {
        float hid[12];
        #pragma unroll
        for (int jj = 0; jj < 12; ++jj) {
            float v = sb1[jj];
            if (qrow == kk + j) v += sw1[0][jj];
            v = fmaf(xp[0][j], sw1[1][jj], v);
            v = fmaf(xp[1][j], sw1[2][jj], v);
            v = fmaf(xp[2][j], sw1[3][jj], v);
            v = fmaf(xp[3][j], sw1[4][jj], v);
            v = fmaf(xp[4][j], sw1[5][jj], v);
            hid[jj] = fmaxf(v, 0.f);
        }
        #pragma unroll
        for (int h = 0; h < 8; ++h) {
            float a = sb2[h];
            #pragma unroll
            for (int jj = 0; jj < 12; ++jj) a = fmaf(hid[jj], sw2[jj][h], a);
            outh[h][j] = a;
        }
    }
    #pragma unroll
    for (int h = 0; h < 8; ++h) {
        const long off = ((long)(b*Hh+h))*NNl + (long)qrow*Nn + kk;
        if (BF16OUT) {
            ushort4 u;
            u.x = f2bf(outh[h][0]); u.y = f2bf(outh[h][1]);
            u.z = f2bf(outh[h][2]); u.w = f2bf(outh[h][3]);
            *(ushort4*)((unsigned short*)biasOut + off) = u;
        } else {
            float4 o = {outh[h][0], outh[h][1], outh[h][2], outh[h][3]};
            *(float4*)((float*)biasOut + off) = o;
        }
    }
}

// ---------------------------------------------------------------------------
// Kernel 4: attention. kvs is XOR-swizzled (T2): row stride 68 floats,
// 16B slot s of row r lives at  r*68 + ((s ^ ((r>>2)&7))<<2).
// Write + both read paths use kswz -> correctness-neutral, kills the 8-way
// bank conflict on pass-1 K reads (rows kg*4+j previously hit 2 bank-quads).
// ---------------------------------------------------------------------------
__device__ inline int kswz(int row, int slot) {
    return row * 68 + (((slot ^ ((row >> 2) & 7)) & 15) << 2);
}

template<bool BF16B>
__global__ __launch_bounds__(256)
void attn2(const float* __restrict__ qkv, const void* __restrict__ biasT,
           const int* __restrict__ mask,
           float* __restrict__ ctx, float* __restrict__ wout)
{
    __shared__ float scT[512][17];    // 34816 B: scores^T [key][q]
    __shared__ float kvs[64 * 68];    // 17408 B: swizzled K/V tile + scratch

    const int qt = blockIdx.x, b = blockIdx.y;
    const int q0 = qt * 16;
    const int tid = threadIdx.x;

    const int qi = tid >> 4;          // pass1/pass2 q-row 0..15
    const int kg = tid & 15;          // pass1 key group (4 keys)
    const int kq = tid >> 6;          // pass3: wave id -> k split
    const int qg = (tid >> 4) & 3;    // pass3: 4 q rows
    const int dg = tid & 15;          // pass3: 4 dims

    float wacc[32];
    #pragma unroll
    for (int i = 0; i < 32; ++i) wacc[i] = 0.f;

    for (int h = 0; h < Hh; ++h) {
        float4 qreg[16];
        {
            const float* qp = qkv + ((long)b*Nn + q0 + qi)*(3*Dd) + h*HD;
            #pragma unroll
            for (int t = 0; t < 16; ++t) qreg[t] = *(const float4*)&qp[t*4];
        }

        // ------------------ pass 1: scores -> scT ------------------
        for (int kt = 0; kt < 8; ++kt) {
            {   // stage K tile [64 rows][16 slots], swizzled
                const int row = tid >> 2;
                const int sb  = (tid & 3) * 4;
                const float* kp = qkv + ((long)b*Nn + kt*64 + row)*(3*Dd)
                                  + Dd + h*HD + sb*4;
                #pragma unroll
                for (int t = 0; t < 4; ++t)
                    *(float4*)&kvs[kswz(row, sb + t)] = *(const float4*)&kp[t*4];
            }
            __syncthreads();

            const int kbase = kt*64 + kg*4;
            const int4 m4 = *(const int4*)&mask[(long)b*Nn + kbase];
            float bias4[4];
            if (BF16B) {
                ushort4 u = *(const ushort4*)((const unsigned short*)biasT
                            + ((long)(b*Hh+h))*NNl + (long)(q0+qi)*Nn + kbase);
                bias4[0] = bf2f(u.x); bias4[1] = bf2f(u.y);
                bias4[2] = bf2f(u.z); bias4[3] = bf2f(u.w);
            } else {
                float4 f = *(const float4*)((const float*)biasT
                            + ((long)(b*Hh+h))*NNl + (long)(q0+qi)*Nn + kbase);
                bias4[0]=f.x; bias4[1]=f.y; bias4[2]=f.z; bias4[3]=f.w;
            }
            const int mm[4] = {m4.x, m4.y, m4.z, m4.w};
            #pragma unroll
            for (int j = 0; j < 4; ++j) {
                const int krow = kg*4 + j;
                float s = 0.f;
                #pragma unroll
                for (int d4 = 0; d4 < 16; ++d4) {
                    float4 k4 = *(const float4*)&kvs[kswz(krow, d4)];
                    s += qreg[d4].x*k4.x + qreg[d4].y*k4.y
                       + qreg[d4].z*k4.z + qreg[d4].w*k4.w;
                }
                float sv = s * 0.125f + bias4[j];
                if (!mm[j]) sv = -1e9f;
                scT[kbase + j][qi] = sv;
            }
            __syncthreads();
        }

        // ------------------ pass 2: softmax (probs stay in regs) ------------------
        {
            const int c = kg;
            float pv[32];
            float mx = -INFINITY;
            #pragma unroll
            for (int i = 0; i < 32; ++i) {
                pv[i] = scT[c + 16*i][qi];
                mx = fmaxf(mx, pv[i]);
            }
            #pragma unroll
            for (int o = 1; o < 16; o <<= 1) mx = fmaxf(mx, __shfl_xor(mx, o));
            float sum = 0.f;
            #pragma unroll
            for (int i = 0; i < 32; ++i) { pv[i] = expf(pv[i] - mx); sum += pv[i]; }
            #pragma unroll
            for (int o = 1; o < 16; o <<= 1) sum += __shfl_xor(sum, o);
            const float inv = 1.f / sum;
            #pragma unroll
            for (int i = 0; i < 32; ++i) {
                const float p = pv[i] * inv;
                scT[c + 16*i][qi] = p;
                wacc[i] += p;
            }
        }
        __syncthreads();

        // ------------------ pass 3: ctx = P @ V ------------------
        float4 acc[4];
        #pragma unroll
        for (int i = 0; i < 4; ++i) acc[i] = make_float4(0.f, 0.f, 0.f, 0.f);

        for (int kt = 0; kt < 8; ++kt) {
            {   // stage V tile, swizzled
                const int row = tid >> 2;
                const int sb  = (tid & 3) * 4;
                const float* vp = qkv + ((long)b*Nn + kt*64 + row)*(3*Dd)
                                  + 2*Dd + h*HD + sb*4;
                #pragma unroll
                for (int t = 0; t < 4; ++t)
                    *(float4*)&kvs[kswz(row, sb + t)] = *(const float4*)&vp[t*4];
            }
            __syncthreads();

            #pragma unroll
            for (int kk2 = 0; kk2 < 16; ++kk2) {
                const int kl = kq*16 + kk2;
                const int k  = kt*64 + kl;
                float p0 = scT[k][qg*4+0];
                float p1 = scT[k][qg*4+1];
                float p2 = scT[k][qg*4+2];
                float p3 = scT[k][qg*4+3];
                float4 v4 = *(const float4*)&kvs[kswz(kl, dg)];
                acc[0].x = fmaf(p0, v4.x, acc[0].x); acc[0].y = fmaf(p0, v4.y, acc[0].y);
                acc[0].z = fmaf(p0, v4.z, acc[0].z); acc[0].w = fmaf(p0, v4.w, acc[0].w);
                acc[1].x = fmaf(p1, v4.x, acc[1].x); acc[1].y = fmaf(p1, v4.y, acc[1].y);
                acc[1].z = fmaf(p1, v4.z, acc[1].z); acc[1].w = fmaf(p1, v4.w, acc[1].w);
                acc[2].x = fmaf(p2, v4.x, acc[2].x); acc[2].y = fmaf(p2, v4.y, acc[2].y);
                acc[2].z = fmaf(p2, v4.z, acc[2].z); acc[2].w = fmaf(p2, v4.w, acc[2].w);
                acc[3].x = fmaf(p3, v4.x, acc[3].x); acc[3].y = fmaf(p3, v4.y, acc[3].y);
                acc[3].z = fmaf(p3, v4.z, acc[3].z); acc[3].w = fmaf(p3, v4.w, acc[3].w);
            }
            __syncthreads();
        }

        // k-split reduce via kvs scratch (linear indexing; phase-separated)
        if (kq > 0) {
            float* dst = &kvs[0] + ((long)(kq-1)*64 + (qg*16 + dg)) * 16;
            #pragma unroll
            for (int i = 0; i < 4; ++i) *(float4*)&dst[i*4] = acc[i];
        }
        __syncthreads();
        if (kq == 0) {
            #pragma unroll
            for (int k2 = 0; k2 < 3; ++k2) {
                const float* src = &kvs[0] + ((long)k2*64 + (qg*16 + dg)) * 16;
                #pragma unroll
                for (int i = 0; i < 4; ++i) {
                    float4 t = *(const float4*)&src[i*4];
                    acc[i].x += t.x; acc[i].y += t.y; acc[i].z += t.z; acc[i].w += t.w;
                }
            }
            #pragma unroll
            for (int i = 0; i < 4; ++i)
                *(float4*)&ctx[((long)b*Nn + q0 + qg*4 + i)*Dd + h*HD + dg*4] = acc[i];
        }
        __syncthreads();
    }

    {
        float* wrow = wout + ((long)b*Nn + q0 + qi) * Nn;
        #pragma unroll
        for (int i = 0; i < 32; ++i) wrow[kg + 16*i] = wacc[i] * 0.125f;
    }
}

// ---------------------------------------------------------------------------
extern "C" void kernel_launch(void* const* d_in, const int* in_sizes, int n_in,
                              void* d_out, int out_size, void* d_ws, size_t ws_size,
                              hipStream_t stream)
{
    const float* h_in      = (const float*)d_in[0];
    const float* adj       = (const float*)d_in[1];
    const int*   mask      = (const int*)d_in[2];
    const float* in_proj_w = (const float*)d_in[3];
    const float* in_proj_b = (const float*)d_in[4];
    const float* out_w     = (const float*)d_in[5];
    const float* out_b     = (const float*)d_in[6];
    const float* ffn_w1    = (const float*)d_in[7];
    const float* ffn_b1    = (const float*)d_in[8];
    const float* ffn_w2    = (const float*)d_in[9];
    const float* ffn_b2    = (const float*)d_in[10];

    float* ws = (float*)d_ws;

    // Region layout (bytes):
    //   [0, 83886080)        : powers P^1..P^5 (5*BNN fp32) -- dead after bias_ffn
    //   [0, 50331648)        : qkv (overlays powers AFTER bias_ffn)
    //   [50331648, 67108864) : ctx
    //   [83886080, ...)      : bias fp32 (134 MB) or bf16 (67 MB)
    float* powers = ws;
    float* qkv    = ws;
    float* ctxb   = ws + 12582912;
    void*  biasT  = (void*)((char*)d_ws + 83886080);

    const bool fp32bias = (ws_size >= 218103808ull);

    float* out_atten = (float*)d_out;
    float* out_wts   = out_atten + BNNl;

    // P^1
    computeP<<<dim3(Nn, Bz), 64, 0, stream>>>(adj, mask, powers);

    // P^2..P^5 (128x64 tiles: 512 blocks = 2/CU)
    for (int s = 1; s < 5; ++s) {
        gemm64<false, false><<<dim3(8, 4, Bz), 256, 0, stream>>>(
            powers + (long)(s-1)*BNNl, powers, nullptr, powers + (long)s*BNNl,
            Nn, Nn, Nn, NNl, NNl, NNl);
    }

    // edge-FFN bias
    if (fp32bias)
        bias_ffn<false><<<dim3(Nn/2, Bz), 256, 0, stream>>>(
            powers, ffn_w1, ffn_b1, ffn_w2, ffn_b2, biasT);
    else
        bias_ffn<true><<<dim3(Nn/2, Bz), 256, 0, stream>>>(
            powers, ffn_w1, ffn_b1, ffn_w2, ffn_b2, biasT);

    // qkv = h @ in_proj_w^T + b  (768 blocks = 3/CU already)
    gemm128<true, true><<<dim3(12, 4, Bz), 256, 0, stream>>>(
        h_in, in_proj_w, in_proj_b, qkv,
        Nn, 3*Dd, Dd, (long)Nn*Dd, 0, (long)Nn*3*Dd);

    // attention
    if (fp32bias)
        attn2<false><<<dim3(Nn/16, Bz), 256, 0, stream>>>(qkv, biasT, mask, ctxb, out_wts);
    else
        attn2<true><<<dim3(Nn/16, Bz), 256, 0, stream>>>(qkv, biasT, mask, ctxb, out_wts);

    // atten_out = ctx @ out_w^T + out_b (128x64 tiles: 512 blocks)
    gemm64<true, true><<<dim3(8, 4, Bz), 256, 0, stream>>>(
        ctxb, out_w, out_b, out_atten,
        Nn, Dd, Dd, (long)Nn*Dd, 0, (long)Nn*Dd);
}